// Round 5
// baseline (1434.441 us; speedup 1.0000x reference)
//
#include <hip/hip_runtime.h>

// DA-RNN forward, fully fused: one block per batch element (B=512).
// R4: 1024-thread blocks, each GATE ROW split across a lane PAIR so
// per-thread weight arrays fit the observed 128-VGPR budget (3 rounds of
// occupancy attributes never lifted it; 87MB/launch scratch traffic said
// the ~200-float arrays spilled). enc: 32 wih + 64 whh; dec: 64 whh +
// 32 w1 + 8 epr. Pair combine = __shfl_xor(a,1). enc_proj weights stream
// from global (L2-shared across blocks) instead of registers.

__device__ __forceinline__ float fast_rcp(float x) {
    return __builtin_amdgcn_rcpf(x);
}
__device__ __forceinline__ float fast_tanh(float x) {
    return 1.f - 2.f * fast_rcp(1.f + __expf(2.f * x)); // safe at +-inf
}
__device__ __forceinline__ float fast_sig(float x) {
    return fast_rcp(1.f + __expf(-x));
}

__global__ __attribute__((amdgpu_flat_work_group_size(1024, 1024),
                          amdgpu_waves_per_eu(4, 4)))
void darnn_fused(
    const float* __restrict__ x,                                    // (512,64,64)
    const float* __restrict__ aW,  const float* __restrict__ ab,    // (320),(1)
    const float* __restrict__ eWih, const float* __restrict__ eWhh, // (512,63),(512,128)
    const float* __restrict__ ebih, const float* __restrict__ ebhh, // (512),(512)
    const float* __restrict__ dW1,  const float* __restrict__ db1,  // (128,384),(128)
    const float* __restrict__ W2,                                   // (128)
    const float* __restrict__ dWih, const float* __restrict__ dWhh, // (512,1),(512,128)
    const float* __restrict__ dbih, const float* __restrict__ dbhh, // (512),(512)
    const float* __restrict__ fcW,  const float* __restrict__ fcb,  // (129),(1)
    const float* __restrict__ fcfW, const float* __restrict__ fcfb, // (256),(1)
    float* __restrict__ out)                                        // (512)
{
    const int b   = blockIdx.x;
    const int tid = threadIdx.x;
    const float* xb = x + b * 4096;   // x[b,t,s] = xb[t*64+s]

    __shared__ float s_enc[64 * 128]; // input_encoded[t][e]   32KB
    __shared__ float s_ep [64 * 128]; // enc_proj[t][f] (+b1)  32KB
    __shared__ float s_attn[64];      // encoder input attention (time-invariant)
    __shared__ float s_g[512];        // activated gates
    __shared__ float s_hc[256];       // [h(128); c(128)]
    __shared__ float s_hp[128];       // h@W1h.T + c@W1c.T
    __shared__ float s_sc[64];        // dec scores -> attn
    __shared__ float s_cp[1024];      // context partials
    __shared__ float s_ctx[128];      // context
    __shared__ float s_W2v[128];
    __shared__ float s_fc[130];       // fc_W(129) + fc_b
    __shared__ float s_y[64];         // y_hist column x[b,t,0]
    __shared__ float s_yt;

    float* const s_x = s_ep;          // staged xin; dead before epilogue writes s_ep

    if (tid < 128) s_W2v[tid] = W2[tid];
    if (tid < 130) s_fc[tid] = (tid < 129) ? fcW[tid] : fcb[0];
    if (tid < 64)  s_y[tid] = xb[tid * 64];

    const int r  = tid >> 1;          // gate row 0..511
    const int h2 = tid & 1;           // which half of the 128-dot

    // ================= encoder =================
    {
        // stage xin: s_x[t*64+n] = x[b,t,n+1], col 63 zero-padded
#pragma unroll
        for (int i = tid; i < 4096; i += 1024)
            s_x[i] = ((i & 63) != 63) ? xb[i + 1] : 0.f;
        if (tid < 128) s_hc[tid] = 0.f;
        __syncthreads();

        // wave 0: time-invariant input attention (score h@Wh+c@Wc is a per-row
        // scalar broadcast over series -> cancels in softmax).
        if (tid < 64) {
            float sc = -1e30f;
            if (tid < 63) {
                sc = ab[0];
                for (int t = 0; t < 64; ++t) sc += s_x[t * 64 + tid] * aW[256 + t];
            }
            float m = sc;
#pragma unroll
            for (int off = 32; off; off >>= 1) m = fmaxf(m, __shfl_xor(m, off));
            float e = (tid < 63) ? __expf(sc - m) : 0.f;
            float s = e;
#pragma unroll
            for (int off = 32; off; off >>= 1) s += __shfl_xor(s, off);
            s_attn[tid] = e / s;
        }

        // per-thread HALF-row weights (fit 128 VGPRs; loads overlap wave0 attn)
        float wih[32];
        float whh[64];
#pragma unroll
        for (int j = 0; j < 32; ++j) {
            const int n = h2 * 32 + j;
            wih[j] = (n < 63) ? eWih[r * 63 + n] : 0.f;
        }
#pragma unroll
        for (int j = 0; j < 64; ++j) whh[j] = eWhh[r * 128 + h2 * 64 + j];
        const float bias = ebih[r] + ebhh[r];
        __syncthreads();

        // fold time-invariant attention into wih
#pragma unroll
        for (int j = 0; j < 32; ++j) wih[j] *= s_attn[h2 * 32 + j];

        float c = 0.f; // carried by threads 0..127

        for (int t = 0; t < 64; ++t) {
            // gates: half-dot per lane, pair-combine via shfl_xor(.,1)
            float a0 = 0.f, a1 = 0.f, a2 = 0.f, a3 = 0.f;
#pragma unroll
            for (int j = 0; j < 32; j += 4) {
                float4 v = *(const float4*)&s_x[t * 64 + h2 * 32 + j];
                a0 += wih[j]   * v.x; a1 += wih[j+1] * v.y;
                a2 += wih[j+2] * v.z; a3 += wih[j+3] * v.w;
            }
#pragma unroll
            for (int j = 0; j < 64; j += 4) {
                float4 v = *(const float4*)&s_hc[h2 * 64 + j];
                a0 += whh[j]   * v.x; a1 += whh[j+1] * v.y;
                a2 += whh[j+2] * v.z; a3 += whh[j+3] * v.w;
            }
            float a = (a0 + a1) + (a2 + a3);
            a += __shfl_xor(a, 1);
            if (h2 == 0) {
                const float acc = a + bias;
                const int q = r >> 7; // 0:i 1:f 2:g 3:o
                s_g[r] = (q == 2) ? fast_tanh(acc) : fast_sig(acc);
            }
            __syncthreads();
            if (tid < 128) {
                c = s_g[128 + tid] * c + s_g[tid] * s_g[256 + tid];
                float h = s_g[384 + tid] * fast_tanh(c);
                s_hc[tid] = h;
                s_enc[t * 128 + tid] = h;
            }
            __syncthreads();
        }
    }

    // ====== enc_proj epilogue: s_ep[t][f] = enc[t]@W1e[f] + b1[f] ======
    // Weights streamed from global (shared across all 512 blocks -> L2-hot).
    {
        const int f = tid & 127, tq = tid >> 7; // 8 t-rows per thread
        float acc[8];
        const float b1 = db1[f];
#pragma unroll
        for (int i = 0; i < 8; ++i) acc[i] = b1;
        const float* w1e = dW1 + f * 384 + 256;
        for (int e0 = 0; e0 < 128; e0 += 16) {
            float w[16];
#pragma unroll
            for (int j = 0; j < 16; ++j) w[j] = w1e[e0 + j];
#pragma unroll
            for (int i = 0; i < 8; ++i) {
                const int trow = tq * 8 + i;
#pragma unroll
                for (int j = 0; j < 16; j += 4) {
                    float4 v = *(const float4*)&s_enc[trow * 128 + e0 + j];
                    acc[i] += w[j]   * v.x + w[j+1] * v.y
                            + w[j+2] * v.z + w[j+3] * v.w;
                }
            }
        }
        __syncthreads(); // all s_x (==s_ep) readers done before overwrite
#pragma unroll
        for (int i = 0; i < 8; ++i) s_ep[(tq * 8 + i) * 128 + f] = acc[i];
    }
    if (tid < 256) s_hc[tid] = 0.f; // reset [h;c] for decoder
    __syncthreads();

    // ================= decoder =================
    {
        float whh[64];                       // dec_Whh row r, half h2
#pragma unroll
        for (int j = 0; j < 64; ++j) whh[j] = dWhh[r * 128 + h2 * 64 + j];
        const float bias  = dbih[r] + dbhh[r];
        const float wih_s = dWih[r];

        // P1 weights: [W1h|W1c] row f8, 32-col slice `oct`, chunk order
        // rotated by oct so the 8 oct-lanes hit 8 distinct bank quads.
        const int f8 = tid >> 3, oct = tid & 7;
        float w1o[32];
#pragma unroll
        for (int cc = 0; cc < 8; ++cc) {
            const int cj = (cc + oct) & 7;
#pragma unroll
            for (int q = 0; q < 4; ++q)
                w1o[cc*4 + q] = dW1[f8 * 384 + oct * 32 + cj * 4 + q];
        }
        // P2 slice: ep[tp][p4*8..+8), chunk rotation by p4>>2 (<=2-way alias)
        const int tp = tid >> 4, p4 = tid & 15;
        float epr[8];
#pragma unroll
        for (int cc = 0; cc < 2; ++cc) {
            const int cj = (cc + (p4 >> 2)) & 1;
            float4 v = *(const float4*)&s_ep[tp * 128 + p4 * 8 + cj * 4];
            epr[cc*4] = v.x; epr[cc*4+1] = v.y; epr[cc*4+2] = v.z; epr[cc*4+3] = v.w;
        }
        float c = 0.f; // carried by threads 0..127

        for (int t = 0; t < 64; ++t) {
            // P1: s_hp[f8] = [h;c] . [W1h|W1c][f8]  (8 lanes per f8)
            {
                float a0 = 0.f, a1 = 0.f, a2 = 0.f, a3 = 0.f;
#pragma unroll
                for (int cc = 0; cc < 8; ++cc) {
                    const int cj = (cc + oct) & 7;
                    float4 v = *(const float4*)&s_hc[oct * 32 + cj * 4];
                    a0 += w1o[cc*4]   * v.x; a1 += w1o[cc*4+1] * v.y;
                    a2 += w1o[cc*4+2] * v.z; a3 += w1o[cc*4+3] * v.w;
                }
                float a = (a0 + a1) + (a2 + a3);
                a += __shfl_xor(a, 1);
                a += __shfl_xor(a, 2);
                a += __shfl_xor(a, 4);
                if (oct == 0) s_hp[f8] = a;
            }
            __syncthreads();
            // P2: score[tp] = sum_f W2[f]*tanh(ep[tp][f]+hp[f])  (16 lanes/tp)
            {
                float a = 0.f;
#pragma unroll
                for (int cc = 0; cc < 2; ++cc) {
                    const int cj = (cc + (p4 >> 2)) & 1;
                    float4 hv = *(const float4*)&s_hp [p4 * 8 + cj * 4];
                    float4 wv = *(const float4*)&s_W2v[p4 * 8 + cj * 4];
                    a += wv.x * fast_tanh(epr[cc*4]   + hv.x);
                    a += wv.y * fast_tanh(epr[cc*4+1] + hv.y);
                    a += wv.z * fast_tanh(epr[cc*4+2] + hv.z);
                    a += wv.w * fast_tanh(epr[cc*4+3] + hv.w);
                }
                a += __shfl_xor(a, 1);
                a += __shfl_xor(a, 2);
                a += __shfl_xor(a, 4);
                a += __shfl_xor(a, 8);
                if (p4 == 0) s_sc[tp] = a;
            }
            __syncthreads();
            // P3: softmax over 64 scores (wave 0)
            if (tid < 64) {
                float sc = s_sc[tid];
                float m = sc;
#pragma unroll
                for (int off = 32; off; off >>= 1) m = fmaxf(m, __shfl_xor(m, off));
                float e = __expf(sc - m);
                float s = e;
#pragma unroll
                for (int off = 32; off; off >>= 1) s += __shfl_xor(s, off);
                s_sc[tid] = e / s;
            }
            __syncthreads();
            // P4: context partials (8 t' per thread)
            {
                const int e = tid & 127, q8 = tid >> 7;
                float a0 = 0.f, a1 = 0.f;
#pragma unroll
                for (int i = 0; i < 8; i += 2) {
                    a0 += s_sc[q8 * 8 + i]     * s_enc[(q8 * 8 + i)     * 128 + e];
                    a1 += s_sc[q8 * 8 + i + 1] * s_enc[(q8 * 8 + i + 1) * 128 + e];
                }
                s_cp[tid] = a0 + a1;
            }
            __syncthreads();
            // P5': wave0 finishes ctx + y_tilde; ALL threads do half-whh dot
            if (tid < 64) {
                float clo = 0.f, chi = 0.f;
#pragma unroll
                for (int q = 0; q < 8; ++q) {
                    clo += s_cp[tid + 128 * q];
                    chi += s_cp[64 + tid + 128 * q];
                }
                s_ctx[tid]      = clo;
                s_ctx[64 + tid] = chi;
                float a = clo * s_fc[tid] + chi * s_fc[64 + tid];
#pragma unroll
                for (int off = 32; off; off >>= 1) a += __shfl_xor(a, off);
                if (tid == 0) s_yt = a + s_y[t] * s_fc[128] + s_fc[129];
            }
            float ah;
            {
                float a0 = 0.f, a1 = 0.f, a2 = 0.f, a3 = 0.f;
#pragma unroll
                for (int j = 0; j < 64; j += 4) {
                    float4 v = *(const float4*)&s_hc[h2 * 64 + j];
                    a0 += whh[j]   * v.x; a1 += whh[j+1] * v.y;
                    a2 += whh[j+2] * v.z; a3 += whh[j+3] * v.w;
                }
                ah = (a0 + a1) + (a2 + a3);
            }
            __syncthreads();
            // P6: gates (pair-combine)
            {
                float a = ah + __shfl_xor(ah, 1);
                if (h2 == 0) {
                    const float acc = a + bias + s_yt * wih_s;
                    const int q = r >> 7;
                    s_g[r] = (q == 2) ? fast_tanh(acc) : fast_sig(acc);
                }
            }
            __syncthreads();
            // P7: LSTM state update
            if (tid < 128) {
                c = s_g[128 + tid] * c + s_g[tid] * s_g[256 + tid];
                float h = s_g[384 + tid] * fast_tanh(c);
                s_hc[tid]       = h;
                s_hc[128 + tid] = c;
            }
            __syncthreads();
        }
    }

    // out[b] = [h, context] . fcf_W + fcf_b
    if (tid < 64) {
        float a = s_hc[tid]       * fcfW[tid]
                + s_hc[64 + tid]  * fcfW[64 + tid]
                + s_ctx[tid]      * fcfW[128 + tid]
                + s_ctx[64 + tid] * fcfW[192 + tid];
#pragma unroll
        for (int off = 32; off; off >>= 1) a += __shfl_xor(a, off);
        if (tid == 0) out[blockIdx.x] = a + fcfb[0];
    }
}

extern "C" void kernel_launch(void* const* d_in, const int* in_sizes, int n_in,
                              void* d_out, int out_size, void* d_ws, size_t ws_size,
                              hipStream_t stream) {
    const float* x      = (const float*)d_in[0];
    const float* aW     = (const float*)d_in[1];
    const float* ab     = (const float*)d_in[2];
    const float* eWih   = (const float*)d_in[3];
    const float* eWhh   = (const float*)d_in[4];
    const float* ebih   = (const float*)d_in[5];
    const float* ebhh   = (const float*)d_in[6];
    const float* dW1    = (const float*)d_in[7];
    const float* db1    = (const float*)d_in[8];
    const float* W2     = (const float*)d_in[9];
    // d_in[10] = dec_b2: constant added before softmax -> cancels, unused.
    const float* dWih   = (const float*)d_in[11];
    const float* dWhh   = (const float*)d_in[12];
    const float* dbih   = (const float*)d_in[13];
    const float* dbhh   = (const float*)d_in[14];
    const float* fcW    = (const float*)d_in[15];
    const float* fcb    = (const float*)d_in[16];
    const float* fcfW   = (const float*)d_in[17];
    const float* fcfb   = (const float*)d_in[18];
    float* out = (float*)d_out;

    darnn_fused<<<dim3(512), dim3(1024), 0, stream>>>(
        x, aW, ab, eWih, eWhh, ebih, ebhh, dW1, db1, W2,
        dWih, dWhh, dbih, dbhh, fcW, fcb, fcfW, fcfb, out);
}

// Round 6
// 1122.980 us; speedup vs baseline: 1.2774x; 1.2774x over previous
//
#include <hip/hip_runtime.h>

// DA-RNN forward, fully fused: one block per batch element (B=512).
// R5: THE VGPR LEVER IS LDS SIZE. rocprof across R1-R4: 512thr/72KB-LDS ->
// 128 VGPR; 1024thr/74KB -> 64 VGPR. The allocator targets the occupancy
// that LDS permits (2 blocks/CU) and caps VGPRs to match; attributes never
// overrode it. Fix: LDS ~90KB (>80KB) -> 1 block/CU -> 2 waves/SIMD ->
// 256-VGPR budget -> the ~233-reg full-row design fits with NO spills.
// Structure = R3 (512 thr, thread j owns gate row j) + dedicated s_x buffer.

__device__ __forceinline__ float fast_rcp(float x) {
    return __builtin_amdgcn_rcpf(x);
}
__device__ __forceinline__ float fast_tanh(float x) {
    return 1.f - 2.f * fast_rcp(1.f + __expf(2.f * x)); // safe at +-inf
}
__device__ __forceinline__ float fast_sig(float x) {
    return fast_rcp(1.f + __expf(-x));
}

__global__ __attribute__((amdgpu_flat_work_group_size(512, 512),
                          amdgpu_waves_per_eu(2, 2)))
void darnn_fused(
    const float* __restrict__ x,                                    // (512,64,64)
    const float* __restrict__ aW,  const float* __restrict__ ab,    // (320),(1)
    const float* __restrict__ eWih, const float* __restrict__ eWhh, // (512,63),(512,128)
    const float* __restrict__ ebih, const float* __restrict__ ebhh, // (512),(512)
    const float* __restrict__ dW1,  const float* __restrict__ db1,  // (128,384),(128)
    const float* __restrict__ W2,                                   // (128)
    const float* __restrict__ dWih, const float* __restrict__ dWhh, // (512,1),(512,128)
    const float* __restrict__ dbih, const float* __restrict__ dbhh, // (512),(512)
    const float* __restrict__ fcW,  const float* __restrict__ fcb,  // (129),(1)
    const float* __restrict__ fcfW, const float* __restrict__ fcfb, // (256),(1)
    float* __restrict__ out)                                        // (512)
{
    const int b   = blockIdx.x;
    const int tid = threadIdx.x;
    const float* xb = x + b * 4096;   // x[b,t,s] = xb[t*64+s]

    __shared__ float s_enc[64 * 128]; // input_encoded[t][e]   32KB
    __shared__ float s_ep [64 * 128]; // enc_proj[t][f] (+b1)  32KB
    __shared__ float s_x  [64 * 64];  // staged xin            16KB (drives LDS>80KB)
    __shared__ float s_attn[64];      // encoder input attention (time-invariant)
    __shared__ float s_g[512];        // activated gates
    __shared__ float s_hc[256];       // [h(128); c(128)]
    __shared__ float s_hp[128];       // h@W1h.T + c@W1c.T
    __shared__ float s_sc[64];        // dec scores -> attn
    __shared__ float s_cp[512];       // context partials
    __shared__ float s_ctx[128];      // context
    __shared__ float s_W2v[128];
    __shared__ float s_fc[130];       // fc_W(129) + fc_b
    __shared__ float s_y[64];         // y_hist column x[b,t,0]
    __shared__ float s_yt;

    if (tid < 128) s_W2v[tid] = W2[tid];
    if (tid < 130) s_fc[tid] = (tid < 129) ? fcW[tid] : fcb[0];
    if (tid < 64)  s_y[tid] = xb[tid * 64];

    // ================= encoder =================
    {
        // stage xin into LDS: s_x[t*64+n] = x[b,t,n+1], col 63 zero-padded
#pragma unroll
        for (int i = tid; i < 4096; i += 512)
            s_x[i] = ((i & 63) != 63) ? xb[i + 1] : 0.f;
        if (tid < 128) s_hc[tid] = 0.f;
        __syncthreads();

        // wave 0: time-invariant input attention. score = h@Wh + c@Wc is a
        // per-row SCALAR broadcast over series -> cancels in softmax:
        // attn = softmax_n( sum_t x[b,t,n+1]*Wt[t] + ab ).
        if (tid < 64) {
            float sc = -1e30f;
            if (tid < 63) {
                sc = ab[0];
                for (int t = 0; t < 64; ++t) sc += s_x[t * 64 + tid] * aW[256 + t];
            }
            float m = sc;
#pragma unroll
            for (int off = 32; off; off >>= 1) m = fmaxf(m, __shfl_xor(m, off));
            float e = (tid < 63) ? __expf(sc - m) : 0.f;
            float s = e;
#pragma unroll
            for (int off = 32; off; off >>= 1) s += __shfl_xor(s, off);
            s_attn[tid] = e / s;
        }

        // per-thread full-row weights (global loads overlap wave0's attn work)
        float wih[64];
        float whh[128];
#pragma unroll
        for (int n = 0; n < 63; ++n) wih[n] = eWih[tid * 63 + n];
        wih[63] = 0.f;
#pragma unroll
        for (int k = 0; k < 128; ++k) whh[k] = eWhh[tid * 128 + k];
        const float bias = ebih[tid] + ebhh[tid];
        __syncthreads();

        // fold time-invariant attention into wih
#pragma unroll
        for (int n = 0; n < 64; ++n) wih[n] *= s_attn[n];

        // pipelined x-dot for t=0
        float xa;
        {
            float a0 = 0.f, a1 = 0.f, a2 = 0.f, a3 = 0.f;
#pragma unroll
            for (int n = 0; n < 64; n += 4) {
                float4 v = *(const float4*)&s_x[n];
                a0 += wih[n]   * v.x; a1 += wih[n+1] * v.y;
                a2 += wih[n+2] * v.z; a3 += wih[n+3] * v.w;
            }
            xa = (a0 + a1) + (a2 + a3);
        }
        float c = 0.f; // carried by threads 0..127

        for (int t = 0; t < 64; ++t) {
            // phase C: gates = act( bias + xa + h.whh )
            float a0 = bias + xa, a1 = 0.f, a2 = 0.f, a3 = 0.f;
#pragma unroll
            for (int k = 0; k < 128; k += 4) {
                float4 v = *(const float4*)&s_hc[k];
                a0 += whh[k]   * v.x; a1 += whh[k+1] * v.y;
                a2 += whh[k+2] * v.z; a3 += whh[k+3] * v.w;
            }
            const float acc = (a0 + a1) + (a2 + a3);
            const int q = tid >> 7; // 0:i 1:f 2:g 3:o
            s_g[tid] = (q == 2) ? fast_tanh(acc) : fast_sig(acc);
            __syncthreads();
            // phase B: state update (2 waves) + next-step x-dot (all waves)
            if (tid < 128) {
                c = s_g[128 + tid] * c + s_g[tid] * s_g[256 + tid];
                float h = s_g[384 + tid] * fast_tanh(c);
                s_hc[tid] = h;
                s_enc[t * 128 + tid] = h;
            }
            if (t < 63) {
                float b0 = 0.f, b1 = 0.f, b2 = 0.f, b3 = 0.f;
#pragma unroll
                for (int n = 0; n < 64; n += 4) {
                    float4 v = *(const float4*)&s_x[(t + 1) * 64 + n];
                    b0 += wih[n]   * v.x; b1 += wih[n+1] * v.y;
                    b2 += wih[n+2] * v.z; b3 += wih[n+3] * v.w;
                }
                xa = (b0 + b1) + (b2 + b3);
            }
            __syncthreads();
        }
    }

    // ============ enc_proj epilogue: s_ep[t][f] = enc[t]@W1e[f] + b1[f] ============
    {
        const int f = tid & 127, tq = tid >> 7;
        float w1e[128];
#pragma unroll
        for (int e = 0; e < 128; ++e) w1e[e] = dW1[f * 384 + 256 + e];
        const float b1 = db1[f];
        for (int i = 0; i < 16; ++i) {
            const int trow = tq * 16 + i;
            float a0 = b1, a1 = 0.f, a2 = 0.f, a3 = 0.f;
#pragma unroll
            for (int e = 0; e < 128; e += 4) {
                float4 v = *(const float4*)&s_enc[trow * 128 + e];
                a0 += w1e[e]   * v.x; a1 += w1e[e+1] * v.y;
                a2 += w1e[e+2] * v.z; a3 += w1e[e+3] * v.w;
            }
            s_ep[trow * 128 + f] = (a0 + a1) + (a2 + a3);
        }
    }
    if (tid < 256) s_hc[tid] = 0.f; // reset [h;c] for decoder
    __syncthreads();

    // ================= decoder =================
    {
        // per-thread weights
        float whh[128];                      // dec_Whh row tid
#pragma unroll
        for (int k = 0; k < 128; ++k) whh[k] = dWhh[tid * 128 + k];
        const float bias  = dbih[tid] + dbhh[tid];
        const float wih_s = dWih[tid];       // (512,1)
        const int f4 = tid >> 2, qq = tid & 3, qq2 = (tid & 3) * 2;
        // w1: [W1h|W1c] row f4, quarter qq, chunk order ROTATED by qq*2 so the
        // 4 qq-lanes hit 4 distinct LDS bank quads in P1.
        float w1[64];
#pragma unroll
        for (int j = 0; j < 16; ++j) {
            const int cj = (j + qq2) & 15;
#pragma unroll
            for (int r = 0; r < 4; ++r)
                w1[4*j + r] = dW1[f4 * 384 + qq * 64 + cj * 4 + r];
        }
        // this thread's fixed ep slice, chunk order ROTATED by p for P2
        const int tp = tid >> 3, p = tid & 7;
        float epr[16];
#pragma unroll
        for (int cc = 0; cc < 4; ++cc) {
            const int cj = (cc + p) & 3;
            float4 v = *(const float4*)&s_ep[tid * 16 + cj * 4];
            epr[4*cc] = v.x; epr[4*cc+1] = v.y; epr[4*cc+2] = v.z; epr[4*cc+3] = v.w;
        }
        float c = 0.f; // carried by threads 0..127

        for (int t = 0; t < 64; ++t) {
            // P1: s_hp[f] = [h;c] . [W1h|W1c][f]   (4 lanes per f, rotated chunks)
            {
                float a0 = 0.f, a1 = 0.f, a2 = 0.f, a3 = 0.f;
#pragma unroll
                for (int j = 0; j < 16; ++j) {
                    const int cj = (j + qq2) & 15;
                    float4 v = *(const float4*)&s_hc[qq * 64 + cj * 4];
                    a0 += w1[4*j]   * v.x; a1 += w1[4*j+1] * v.y;
                    a2 += w1[4*j+2] * v.z; a3 += w1[4*j+3] * v.w;
                }
                float a = (a0 + a1) + (a2 + a3);
                a += __shfl_xor(a, 1);
                a += __shfl_xor(a, 2);
                if (qq == 0) s_hp[f4] = a;
            }
            __syncthreads();
            // P2: score[tp] = sum_f W2[f]*tanh(ep[tp][f]+hp[f])  (8 lanes per tp)
            {
                float a = 0.f;
#pragma unroll
                for (int cc = 0; cc < 4; ++cc) {
                    const int cj = (cc + p) & 3;
                    float4 hv = *(const float4*)&s_hp [p * 16 + cj * 4];
                    float4 wv = *(const float4*)&s_W2v[p * 16 + cj * 4];
                    const int i0 = cc * 4;
                    a += wv.x * fast_tanh(epr[i0]   + hv.x);
                    a += wv.y * fast_tanh(epr[i0+1] + hv.y);
                    a += wv.z * fast_tanh(epr[i0+2] + hv.z);
                    a += wv.w * fast_tanh(epr[i0+3] + hv.w);
                }
                a += __shfl_xor(a, 1);
                a += __shfl_xor(a, 2);
                a += __shfl_xor(a, 4);
                if (p == 0) s_sc[tp] = a;
            }
            __syncthreads();
            // P3: softmax over 64 scores (wave 0)
            if (tid < 64) {
                float sc = s_sc[tid];
                float m = sc;
#pragma unroll
                for (int off = 32; off; off >>= 1) m = fmaxf(m, __shfl_xor(m, off));
                float e = __expf(sc - m);
                float s = e;
#pragma unroll
                for (int off = 32; off; off >>= 1) s += __shfl_xor(s, off);
                s_sc[tid] = e / s;
            }
            __syncthreads();
            // P4: context partials over t' quarters
            {
                const int e = tid & 127, q2 = tid >> 7;
                float a0 = 0.f, a1 = 0.f;
#pragma unroll
                for (int i = 0; i < 16; i += 2) {
                    a0 += s_sc[q2 * 16 + i]     * s_enc[(q2 * 16 + i)     * 128 + e];
                    a1 += s_sc[q2 * 16 + i + 1] * s_enc[(q2 * 16 + i + 1) * 128 + e];
                }
                s_cp[tid] = a0 + a1;
            }
            __syncthreads();
            // P5': wave0 finishes ctx + y_tilde while ALL threads do the whh dot
            if (tid < 64) {
                const float clo = s_cp[tid]       + s_cp[128 + tid]
                                + s_cp[256 + tid] + s_cp[384 + tid];
                const float chi = s_cp[64 + tid]  + s_cp[192 + tid]
                                + s_cp[320 + tid] + s_cp[448 + tid];
                s_ctx[tid]      = clo;
                s_ctx[64 + tid] = chi;
                float a = clo * s_fc[tid] + chi * s_fc[64 + tid];
#pragma unroll
                for (int off = 32; off; off >>= 1) a += __shfl_xor(a, off);
                if (tid == 0) s_yt = a + s_y[t] * s_fc[128] + s_fc[129];
            }
            float a_hh;
            {
                float a0 = bias, a1 = 0.f, a2 = 0.f, a3 = 0.f;
#pragma unroll
                for (int k = 0; k < 128; k += 4) {
                    float4 v = *(const float4*)&s_hc[k];
                    a0 += whh[k]   * v.x; a1 += whh[k+1] * v.y;
                    a2 += whh[k+2] * v.z; a3 += whh[k+3] * v.w;
                }
                a_hh = (a0 + a1) + (a2 + a3);
            }
            __syncthreads();
            // P6: gates
            {
                const float acc = a_hh + s_yt * wih_s;
                const int q = tid >> 7;
                s_g[tid] = (q == 2) ? fast_tanh(acc) : fast_sig(acc);
            }
            __syncthreads();
            // P7: LSTM state update
            if (tid < 128) {
                c = s_g[128 + tid] * c + s_g[tid] * s_g[256 + tid];
                float h = s_g[384 + tid] * fast_tanh(c);
                s_hc[tid]       = h;
                s_hc[128 + tid] = c;
            }
            __syncthreads();
        }
    }

    // out[b] = [h, context] . fcf_W + fcf_b
    if (tid < 64) {
        float a = s_hc[tid]       * fcfW[tid]
                + s_hc[64 + tid]  * fcfW[64 + tid]
                + s_ctx[tid]      * fcfW[128 + tid]
                + s_ctx[64 + tid] * fcfW[192 + tid];
#pragma unroll
        for (int off = 32; off; off >>= 1) a += __shfl_xor(a, off);
        if (tid == 0) out[blockIdx.x] = a + fcfb[0];
    }
}

extern "C" void kernel_launch(void* const* d_in, const int* in_sizes, int n_in,
                              void* d_out, int out_size, void* d_ws, size_t ws_size,
                              hipStream_t stream) {
    const float* x      = (const float*)d_in[0];
    const float* aW     = (const float*)d_in[1];
    const float* ab     = (const float*)d_in[2];
    const float* eWih   = (const float*)d_in[3];
    const float* eWhh   = (const float*)d_in[4];
    const float* ebih   = (const float*)d_in[5];
    const float* ebhh   = (const float*)d_in[6];
    const float* dW1    = (const float*)d_in[7];
    const float* db1    = (const float*)d_in[8];
    const float* W2     = (const float*)d_in[9];
    // d_in[10] = dec_b2: constant added before softmax -> cancels, unused.
    const float* dWih   = (const float*)d_in[11];
    const float* dWhh   = (const float*)d_in[12];
    const float* dbih   = (const float*)d_in[13];
    const float* dbhh   = (const float*)d_in[14];
    const float* fcW    = (const float*)d_in[15];
    const float* fcb    = (const float*)d_in[16];
    const float* fcfW   = (const float*)d_in[17];
    const float* fcfb   = (const float*)d_in[18];
    float* out = (float*)d_out;

    darnn_fused<<<dim3(512), dim3(512), 0, stream>>>(
        x, aW, ab, eWih, eWhh, ebih, ebhh, dW1, db1, W2,
        dWih, dWhh, dbih, dbhh, fcW, fcb, fcfW, fcfb, out);
}

// Round 7
// 733.118 us; speedup vs baseline: 1.9566x; 1.5318x over previous
//
#include <hip/hip_runtime.h>

// DA-RNN forward, fully fused: one block per batch element (B=512), 512 thr.
// R7: weights in LDS as f16 pairs + v_dot2_f32_f16, NOT per-thread register
// arrays. R1-R6 proved this toolchain pins VGPR=128 for 512-thr blocks no
// matter what (launch_bounds / waves_per_eu / LDS>80KB all ignored), so the
// ~200-float register-resident design always spilled -> 85MB/launch scratch
// traffic = the whole runtime. New layout: whh f16 [k2=56][row=512] dwords
// (112KB, stride-1 -> conflict-free), cols 112..127 kept f32 in 16 regs,
// s_enc/s_ep stored f16. Per-thread arrays <= 80 floats -> fits the cap.

typedef _Float16 half2v __attribute__((ext_vector_type(2)));

#if defined(__has_builtin)
#if __has_builtin(__builtin_amdgcn_fdot2)
#define HAS_FDOT2 1
#endif
#endif

__device__ __forceinline__ float fast_rcp(float x) { return __builtin_amdgcn_rcpf(x); }
__device__ __forceinline__ float fast_tanh(float x) {
    return 1.f - 2.f * fast_rcp(1.f + __expf(2.f * x)); // safe at +-inf
}
__device__ __forceinline__ float fast_sig(float x) { return fast_rcp(1.f + __expf(-x)); }

__device__ __forceinline__ unsigned int packh2(float a, float b) {
    half2v v; v.x = (_Float16)a; v.y = (_Float16)b;   // RNE converts
    return __builtin_bit_cast(unsigned int, v);
}
__device__ __forceinline__ unsigned short packh1(float a) {
    return __builtin_bit_cast(unsigned short, (_Float16)a);
}
__device__ __forceinline__ float unph(unsigned short u) {
    return (float)__builtin_bit_cast(_Float16, u);
}
__device__ __forceinline__ float fdot2f(unsigned int w, unsigned int h, float acc) {
#if HAS_FDOT2
    return __builtin_amdgcn_fdot2(__builtin_bit_cast(half2v, w),
                                  __builtin_bit_cast(half2v, h), acc, false);
#else
    half2v wv = __builtin_bit_cast(half2v, w);
    half2v hv = __builtin_bit_cast(half2v, h);
    return acc + (float)wv.x * (float)hv.x + (float)wv.y * (float)hv.y;
#endif
}

#define NK2 56   // f16-pair count: cols 0..111; cols 112..127 live in f32 regs

__global__ __launch_bounds__(512) void darnn_fused(
    const float* __restrict__ x,                                    // (512,64,64)
    const float* __restrict__ aW,  const float* __restrict__ ab,    // (320),(1)
    const float* __restrict__ eWih, const float* __restrict__ eWhh, // (512,63),(512,128)
    const float* __restrict__ ebih, const float* __restrict__ ebhh, // (512),(512)
    const float* __restrict__ dW1,  const float* __restrict__ db1,  // (128,384),(128)
    const float* __restrict__ W2,                                   // (128)
    const float* __restrict__ dWih, const float* __restrict__ dWhh, // (512,1),(512,128)
    const float* __restrict__ dbih, const float* __restrict__ dbhh, // (512),(512)
    const float* __restrict__ fcW,  const float* __restrict__ fcb,  // (129),(1)
    const float* __restrict__ fcfW, const float* __restrict__ fcfb, // (256),(1)
    float* __restrict__ out)                                        // (512)
{
    const int b   = blockIdx.x;
    const int tid = threadIdx.x;
    const float* xb = x + b * 4096;   // x[b,t,s] = xb[t*64+s]

    __shared__ unsigned int   s_w16[NK2 * 512];   // 112KB: whh f16 pairs [k2][row]
    __shared__ __align__(16) unsigned char s_rawB[16384]; // s_x f32 (enc) / s_ep f16 (dec)
    __shared__ unsigned short s_enc16[64 * 128];  // 16KB: input_encoded f16
    __shared__ float s_hc[256];      // [h(128); c(128)] f32
    __shared__ unsigned int s_hch[NK2]; // h as f16 pairs (k<112)
    __shared__ float s_g[512];       // activated gates
    __shared__ float s_cp[512];      // context partials
    __shared__ float s_hp[128];      // h@W1h.T + c@W1c.T
    __shared__ float s_attn[64];
    __shared__ float s_sc[64];
    __shared__ float s_ctx[128];
    __shared__ float s_W2v[128];
    __shared__ float s_fc[130];
    __shared__ float s_y[64];
    __shared__ float s_yt;

    float* const s_x = (float*)s_rawB;                      // enc: (64t,64n)
    unsigned short* const s_ep = (unsigned short*)s_rawB;   // dec: (64t,128f) f16

    if (tid < 128) s_W2v[tid] = W2[tid];
    if (tid < 130) s_fc[tid] = (tid < 129) ? fcW[tid] : fcb[0];
    if (tid < 64)  s_y[tid] = xb[tid * 64];

    // ================= encoder =================
    {
        // fill whh-f16 LDS (row tid) + f32 tail regs
        float wtail[16];
#pragma unroll
        for (int k2 = 0; k2 < NK2; ++k2) {
            float2 wv = *(const float2*)&eWhh[tid * 128 + 2 * k2];
            s_w16[k2 * 512 + tid] = packh2(wv.x, wv.y);
        }
#pragma unroll
        for (int k = 0; k < 16; ++k) wtail[k] = eWhh[tid * 128 + 112 + k];

        // stage xin: s_x[t*64+n] = x[b,t,n+1], col 63 zero-padded
#pragma unroll
        for (int i = tid; i < 4096; i += 512)
            s_x[i] = ((i & 63) != 63) ? xb[i + 1] : 0.f;

        // per-thread input weights, row tid (63, padded)
        float wih[64];
        for (int n = 0; n < 63; ++n) wih[n] = eWih[tid * 63 + n];
        wih[63] = 0.f;
        const float bias = ebih[tid] + ebhh[tid];

        if (tid < 128) s_hc[tid] = 0.f;
        if (tid < NK2) s_hch[tid] = 0u;
        __syncthreads();

        // wave0: time-invariant input attention (h@Wh+c@Wc is a per-row scalar
        // broadcast over series -> cancels in softmax).
        if (tid < 64) {
            float sc = -1e30f;
            if (tid < 63) {
                sc = ab[0];
                for (int t = 0; t < 64; ++t) sc += s_x[t * 64 + tid] * aW[256 + t];
            }
            float m = sc;
#pragma unroll
            for (int off = 32; off; off >>= 1) m = fmaxf(m, __shfl_xor(m, off));
            float e = (tid < 63) ? __expf(sc - m) : 0.f;
            float s = e;
#pragma unroll
            for (int off = 32; off; off >>= 1) s += __shfl_xor(s, off);
            s_attn[tid] = e / s;
        }
        __syncthreads();

        // fold time-invariant attention into wih
#pragma unroll
        for (int n = 0; n < 64; ++n) wih[n] *= s_attn[n];

        // pipelined x-dot for t=0
        float xa;
        {
            float a0 = 0.f, a1 = 0.f, a2 = 0.f, a3 = 0.f;
#pragma unroll
            for (int n = 0; n < 64; n += 4) {
                float4 v = *(const float4*)&s_x[n];
                a0 += wih[n]   * v.x; a1 += wih[n+1] * v.y;
                a2 += wih[n+2] * v.z; a3 += wih[n+3] * v.w;
            }
            xa = (a0 + a1) + (a2 + a3);
        }
        float c = 0.f; // carried by threads 0..127

        for (int t = 0; t < 64; ++t) {
            // gates: f16 main dot from LDS + f32 tail from regs
            float a0 = bias + xa, a1 = 0.f, a2 = 0.f, a3 = 0.f;
#pragma unroll
            for (int k2 = 0; k2 < NK2; k2 += 4) {
                a0 = fdot2f(s_w16[(k2+0)*512 + tid], s_hch[k2+0], a0);
                a1 = fdot2f(s_w16[(k2+1)*512 + tid], s_hch[k2+1], a1);
                a2 = fdot2f(s_w16[(k2+2)*512 + tid], s_hch[k2+2], a2);
                a3 = fdot2f(s_w16[(k2+3)*512 + tid], s_hch[k2+3], a3);
            }
#pragma unroll
            for (int k = 0; k < 16; k += 4) {
                float4 v = *(const float4*)&s_hc[112 + k];
                a0 += wtail[k]   * v.x; a1 += wtail[k+1] * v.y;
                a2 += wtail[k+2] * v.z; a3 += wtail[k+3] * v.w;
            }
            const float acc = (a0 + a1) + (a2 + a3);
            const int q = tid >> 7; // 0:i 1:f 2:g 3:o
            s_g[tid] = (q == 2) ? fast_tanh(acc) : fast_sig(acc);
            __syncthreads();
            // state update (2 waves) + next-step x-dot (all waves)
            if (tid < 128) {
                c = s_g[128 + tid] * c + s_g[tid] * s_g[256 + tid];
                float h = s_g[384 + tid] * fast_tanh(c);
                s_hc[tid] = h;
                s_enc16[t * 128 + tid] = packh1(h);
                float hx = __shfl_xor(h, 1);
                if (!(tid & 1) && tid < 112) s_hch[tid >> 1] = packh2(h, hx);
            }
            if (t < 63) {
                float b0 = 0.f, b1 = 0.f, b2 = 0.f, b3 = 0.f;
#pragma unroll
                for (int n = 0; n < 64; n += 4) {
                    float4 v = *(const float4*)&s_x[(t + 1) * 64 + n];
                    b0 += wih[n]   * v.x; b1 += wih[n+1] * v.y;
                    b2 += wih[n+2] * v.z; b3 += wih[n+3] * v.w;
                }
                xa = (b0 + b1) + (b2 + b3);
            }
            __syncthreads();
        }
    }

    // ====== enc_proj epilogue: s_ep[t][f] = enc[t]@W1e[f] + b1[f]  (f16 out) ======
    {
        const int f = tid & 127, tq = tid >> 7; // 16 t-rows per thread
        float acc[16];
        const float b1 = db1[f];
#pragma unroll
        for (int i = 0; i < 16; ++i) acc[i] = b1;
        const float* w1e = dW1 + f * 384 + 256;
        for (int e0 = 0; e0 < 128; e0 += 8) {
            float4 wa = *(const float4*)&w1e[e0];
            float4 wb = *(const float4*)&w1e[e0 + 4];
            const unsigned int wp0 = packh2(wa.x, wa.y), wp1 = packh2(wa.z, wa.w);
            const unsigned int wp2 = packh2(wb.x, wb.y), wp3 = packh2(wb.z, wb.w);
#pragma unroll
            for (int i = 0; i < 16; ++i) {
                const unsigned int* er =
                    (const unsigned int*)&s_enc16[(tq * 16 + i) * 128 + e0];
                float t0 = fdot2f(wp0, er[0], acc[i]);
                t0 = fdot2f(wp1, er[1], t0);
                t0 = fdot2f(wp2, er[2], t0);
                acc[i] = fdot2f(wp3, er[3], t0);
            }
        }
        __syncthreads(); // s_x (==s_ep region) readers all done
#pragma unroll
        for (int i = 0; i < 16; ++i)
            s_ep[(tq * 16 + i) * 128 + f] = packh1(acc[i]);
    }

    // ================= decoder =================
    {
        // refill s_w16 with dec_Whh f16 + f32 tail regs
        float wtail[16];
#pragma unroll
        for (int k2 = 0; k2 < NK2; ++k2) {
            float2 wv = *(const float2*)&dWhh[tid * 128 + 2 * k2];
            s_w16[k2 * 512 + tid] = packh2(wv.x, wv.y);
        }
#pragma unroll
        for (int k = 0; k < 16; ++k) wtail[k] = dWhh[tid * 128 + 112 + k];
        const float bias  = dbih[tid] + dbhh[tid];
        const float wih_s = dWih[tid];       // (512,1)

        // P1 weights: [W1h|W1c] row f4, quarter qq, chunk order ROTATED by
        // qq*2 so the 4 qq-lanes hit distinct LDS bank quads.
        const int f4 = tid >> 2, qq = tid & 3, qq2 = (tid & 3) * 2;
        float w1[64];
#pragma unroll
        for (int j = 0; j < 16; ++j) {
            const int cj = (j + qq2) & 15;
#pragma unroll
            for (int rr = 0; rr < 4; ++rr)
                w1[4*j + rr] = dW1[f4 * 384 + qq * 64 + cj * 4 + rr];
        }
        const int tp = tid >> 3, p = tid & 7;  // P2 geometry
        if (tid < 256) s_hc[tid] = 0.f;
        if (tid < NK2) s_hch[tid] = 0u;
        float c = 0.f; // carried by threads 0..127
        __syncthreads();

        for (int t = 0; t < 64; ++t) {
            // P1: s_hp[f] = [h;c] . [W1h|W1c][f]   (4 lanes per f)
            {
                float a0 = 0.f, a1 = 0.f, a2 = 0.f, a3 = 0.f;
#pragma unroll
                for (int j = 0; j < 16; ++j) {
                    const int cj = (j + qq2) & 15;
                    float4 v = *(const float4*)&s_hc[qq * 64 + cj * 4];
                    a0 += w1[4*j]   * v.x; a1 += w1[4*j+1] * v.y;
                    a2 += w1[4*j+2] * v.z; a3 += w1[4*j+3] * v.w;
                }
                float a = (a0 + a1) + (a2 + a3);
                a += __shfl_xor(a, 1);
                a += __shfl_xor(a, 2);
                if (qq == 0) s_hp[f4] = a;
            }
            __syncthreads();
            // P2: score[tp] = sum_f W2[f]*tanh(ep[tp][f]+hp[f])  (8 lanes/tp,
            // chunk order rotated by tp -> 2-way LDS aliasing, free)
            {
                float a = 0.f;
#pragma unroll
                for (int cc = 0; cc < 4; ++cc) {
                    const int cj = (cc + tp) & 3;
                    const unsigned int* e2 =
                        (const unsigned int*)&s_ep[tp * 128 + p * 16 + cj * 4];
                    const half2v ea = __builtin_bit_cast(half2v, e2[0]);
                    const half2v eb = __builtin_bit_cast(half2v, e2[1]);
                    float4 hv = *(const float4*)&s_hp [p * 16 + cj * 4];
                    float4 wv = *(const float4*)&s_W2v[p * 16 + cj * 4];
                    a += wv.x * fast_tanh((float)ea.x + hv.x);
                    a += wv.y * fast_tanh((float)ea.y + hv.y);
                    a += wv.z * fast_tanh((float)eb.x + hv.z);
                    a += wv.w * fast_tanh((float)eb.y + hv.w);
                }
                a += __shfl_xor(a, 1);
                a += __shfl_xor(a, 2);
                a += __shfl_xor(a, 4);
                if (p == 0) s_sc[tp] = a;
            }
            __syncthreads();
            // P3: softmax over 64 scores (wave 0)
            if (tid < 64) {
                float sc = s_sc[tid];
                float m = sc;
#pragma unroll
                for (int off = 32; off; off >>= 1) m = fmaxf(m, __shfl_xor(m, off));
                float e = __expf(sc - m);
                float s = e;
#pragma unroll
                for (int off = 32; off; off >>= 1) s += __shfl_xor(s, off);
                s_sc[tid] = e / s;
            }
            __syncthreads();
            // P4: context partials over t' quarters (s_enc16 f16)
            {
                const int e = tid & 127, q2 = tid >> 7;
                float a0 = 0.f, a1 = 0.f;
#pragma unroll
                for (int i = 0; i < 16; i += 2) {
                    a0 += s_sc[q2*16 + i]   * unph(s_enc16[(q2*16 + i)   * 128 + e]);
                    a1 += s_sc[q2*16 + i+1] * unph(s_enc16[(q2*16 + i+1) * 128 + e]);
                }
                s_cp[tid] = a0 + a1;
            }
            __syncthreads();
            // P5': wave0 finishes ctx + y_tilde; ALL threads do the whh dot
            if (tid < 64) {
                const float clo = s_cp[tid]       + s_cp[128 + tid]
                                + s_cp[256 + tid] + s_cp[384 + tid];
                const float chi = s_cp[64 + tid]  + s_cp[192 + tid]
                                + s_cp[320 + tid] + s_cp[448 + tid];
                s_ctx[tid]      = clo;
                s_ctx[64 + tid] = chi;
                float a = clo * s_fc[tid] + chi * s_fc[64 + tid];
#pragma unroll
                for (int off = 32; off; off >>= 1) a += __shfl_xor(a, off);
                if (tid == 0) s_yt = a + s_y[t] * s_fc[128] + s_fc[129];
            }
            float a_hh;
            {
                float a0 = bias, a1 = 0.f, a2 = 0.f, a3 = 0.f;
#pragma unroll
                for (int k2 = 0; k2 < NK2; k2 += 4) {
                    a0 = fdot2f(s_w16[(k2+0)*512 + tid], s_hch[k2+0], a0);
                    a1 = fdot2f(s_w16[(k2+1)*512 + tid], s_hch[k2+1], a1);
                    a2 = fdot2f(s_w16[(k2+2)*512 + tid], s_hch[k2+2], a2);
                    a3 = fdot2f(s_w16[(k2+3)*512 + tid], s_hch[k2+3], a3);
                }
#pragma unroll
                for (int k = 0; k < 16; k += 4) {
                    float4 v = *(const float4*)&s_hc[112 + k];
                    a0 += wtail[k]   * v.x; a1 += wtail[k+1] * v.y;
                    a2 += wtail[k+2] * v.z; a3 += wtail[k+3] * v.w;
                }
                a_hh = (a0 + a1) + (a2 + a3);
            }
            __syncthreads();
            // P6: gates
            {
                const float acc = a_hh + s_yt * wih_s;
                const int q = tid >> 7;
                s_g[tid] = (q == 2) ? fast_tanh(acc) : fast_sig(acc);
            }
            __syncthreads();
            // P7: LSTM state update
            if (tid < 128) {
                c = s_g[128 + tid] * c + s_g[tid] * s_g[256 + tid];
                float h = s_g[384 + tid] * fast_tanh(c);
                s_hc[tid]       = h;
                s_hc[128 + tid] = c;
                float hx = __shfl_xor(h, 1);
                if (!(tid & 1) && tid < 112) s_hch[tid >> 1] = packh2(h, hx);
            }
            __syncthreads();
        }
    }

    // out[b] = [h, context] . fcf_W + fcf_b
    if (tid < 64) {
        float a = s_hc[tid]       * fcfW[tid]
                + s_hc[64 + tid]  * fcfW[64 + tid]
                + s_ctx[tid]      * fcfW[128 + tid]
                + s_ctx[64 + tid] * fcfW[192 + tid];
#pragma unroll
        for (int off = 32; off; off >>= 1) a += __shfl_xor(a, off);
        if (tid == 0) out[blockIdx.x] = a + fcfb[0];
    }
}

extern "C" void kernel_launch(void* const* d_in, const int* in_sizes, int n_in,
                              void* d_out, int out_size, void* d_ws, size_t ws_size,
                              hipStream_t stream) {
    const float* x      = (const float*)d_in[0];
    const float* aW     = (const float*)d_in[1];
    const float* ab     = (const float*)d_in[2];
    const float* eWih   = (const float*)d_in[3];
    const float* eWhh   = (const float*)d_in[4];
    const float* ebih   = (const float*)d_in[5];
    const float* ebhh   = (const float*)d_in[6];
    const float* dW1    = (const float*)d_in[7];
    const float* db1    = (const float*)d_in[8];
    const float* W2     = (const float*)d_in[9];
    // d_in[10] = dec_b2: constant added before softmax -> cancels, unused.
    const float* dWih   = (const float*)d_in[11];
    const float* dWhh   = (const float*)d_in[12];
    const float* dbih   = (const float*)d_in[13];
    const float* dbhh   = (const float*)d_in[14];
    const float* fcW    = (const float*)d_in[15];
    const float* fcb    = (const float*)d_in[16];
    const float* fcfW   = (const float*)d_in[17];
    const float* fcfb   = (const float*)d_in[18];
    float* out = (float*)d_out;

    darnn_fused<<<dim3(512), dim3(512), 0, stream>>>(
        x, aW, ab, eWih, eWhh, ebih, ebhh, dW1, db1, W2,
        dWih, dWhh, dbih, dbhh, fcW, fcb, fcfW, fcfb, out);
}

// Round 11
// 635.552 us; speedup vs baseline: 2.2570x; 1.1535x over previous
//
#include <hip/hip_runtime.h>

// DA-RNN forward, fully fused: one block per batch element (B=512), 512 thr.
// R8/R9: weights as PACKED-F16 REGISTER arrays (half the regs of the f32
// attempts that spilled in R1-R6): enc whh = 48 pair-dwords regs + 16-pair LDS
// tail, wih = 32, dec W1-quarter = 32. Kills the per-step LDS weight loads;
// h/x broadcasts widened to b128; LDS ~73KB -> 2 blocks/CU (16 waves) so
// blocks overlap each other's barrier drains. fdot2 (v_dot2_f32_f16).
// R9 fix: x-staging loop bound 4 (not 8) -- k=4..7 read xb[up to 8191], 4KB
// OOB past the batch row -> memory fault (core dump) on b=511.

typedef _Float16 half2v __attribute__((ext_vector_type(2)));
typedef unsigned int uint;

#if defined(__has_builtin)
#if __has_builtin(__builtin_amdgcn_fdot2)
#define HAS_FDOT2 1
#endif
#endif

__device__ __forceinline__ float fast_rcp(float x) { return __builtin_amdgcn_rcpf(x); }
__device__ __forceinline__ float fast_tanh(float x) {
    return 1.f - 2.f * fast_rcp(1.f + __expf(2.f * x)); // safe at +-inf
}
__device__ __forceinline__ float fast_sig(float x) { return fast_rcp(1.f + __expf(-x)); }

__device__ __forceinline__ uint packh2(float a, float b) {
    half2v v; v.x = (_Float16)a; v.y = (_Float16)b;
    return __builtin_bit_cast(uint, v);
}
__device__ __forceinline__ unsigned short packh1(float a) {
    return __builtin_bit_cast(unsigned short, (_Float16)a);
}
__device__ __forceinline__ float unph(unsigned short u) {
    return (float)__builtin_bit_cast(_Float16, u);
}
__device__ __forceinline__ float fdot2f(uint w, uint h, float acc) {
#if HAS_FDOT2
    return __builtin_amdgcn_fdot2(__builtin_bit_cast(half2v, w),
                                  __builtin_bit_cast(half2v, h), acc, false);
#else
    half2v wv = __builtin_bit_cast(half2v, w);
    half2v hv = __builtin_bit_cast(half2v, h);
    return acc + (float)wv.x * (float)hv.x + (float)wv.y * (float)hv.y;
#endif
}

__global__ __launch_bounds__(512) void darnn_fused(
    const float* __restrict__ x,                                    // (512,64,64)
    const float* __restrict__ aW,  const float* __restrict__ ab,    // (320),(1)
    const float* __restrict__ eWih, const float* __restrict__ eWhh, // (512,63),(512,128)
    const float* __restrict__ ebih, const float* __restrict__ ebhh, // (512),(512)
    const float* __restrict__ dW1,  const float* __restrict__ db1,  // (128,384),(128)
    const float* __restrict__ W2,                                   // (128)
    const float* __restrict__ dWih, const float* __restrict__ dWhh, // (512,1),(512,128)
    const float* __restrict__ dbih, const float* __restrict__ dbhh, // (512),(512)
    const float* __restrict__ fcW,  const float* __restrict__ fcb,  // (129),(1)
    const float* __restrict__ fcfW, const float* __restrict__ fcfb, // (256),(1)
    float* __restrict__ out)                                        // (512)
{
    const int b   = blockIdx.x;
    const int tid = threadIdx.x;
    const float* xb = x + b * 4096;   // x[b,t,s] = xb[t*64+s]

    __shared__ __align__(16) uint s_wt[16 * 512];          // 32KB: whh cols 96..127 pairs [k2][row]
    __shared__ __align__(16) unsigned short s_enc16[64*128]; // 16KB: input_encoded f16
    __shared__ __align__(16) uint u[64 * 64];              // 16KB union: x16 (enc, 2048) / ep16 (dec, 4096)
    __shared__ __align__(16) uint s_hch[128];              // h-pairs[0..63] | c-pairs[64..127]
    __shared__ float s_g[512];       // activated gates
    __shared__ float s_cp[512];      // context partials
    __shared__ float s_hp[128];      // W1hc . [h;c]
    __shared__ float s_hcf[128];     // dec h (f32) for final output
    __shared__ float s_attn[64];
    __shared__ float s_sc[64];
    __shared__ float s_ctx[128];
    __shared__ float s_W2v[128];
    __shared__ float s_fc[130];
    __shared__ float s_y[64];
    __shared__ float s_yt;

    uint whh16[48];   // recurrent weights cols 0..95, packed pairs (enc then dec)

    // ================= encoder prologue =================
    uint wih16[32];
    float bias;
    {
        // stage raw xin as f16 pairs: u[t*32+n2] = (x[t,2n2+1], x[t,2n2+2]);
        // 64 rows x 32 uints = 2048 entries (k<4!), col n=63 zero-padded.
#pragma unroll
        for (int k = 0; k < 4; ++k) {
            const int i = tid + 512 * k;
            const int t = i >> 5, n2 = i & 31;
            const float lo = xb[t * 64 + 2 * n2 + 1];
            const float hi = (n2 < 31) ? xb[t * 64 + 2 * n2 + 2] : 0.f;
            u[i] = packh2(lo, hi);
        }
        if (tid < 64)  s_y[tid] = xb[tid * 64];
        if (tid < 128) s_W2v[tid] = W2[tid];
        if (tid < 130) s_fc[tid] = (tid < 129) ? fcW[tid] : fcb[0];
        if (tid < 128) s_hch[tid] = 0u;
#pragma unroll
        for (int j = 0; j < 48; ++j)
            whh16[j] = packh2(eWhh[tid * 128 + 2 * j], eWhh[tid * 128 + 2 * j + 1]);
#pragma unroll
        for (int j = 0; j < 16; ++j)
            s_wt[j * 512 + tid] = packh2(eWhh[tid * 128 + 96 + 2 * j],
                                         eWhh[tid * 128 + 97 + 2 * j]);
#pragma unroll
        for (int j = 0; j < 32; ++j) {
            const float lo = eWih[tid * 63 + 2 * j];
            const float hi = (2 * j + 1 < 63) ? eWih[tid * 63 + 2 * j + 1] : 0.f;
            wih16[j] = packh2(lo, hi);
        }
        bias = ebih[tid] + ebhh[tid];
    }
    __syncthreads();

    // wave0: time-invariant input attention (h@Wh+c@Wc is a per-row scalar
    // broadcast over series -> cancels in softmax).
    if (tid < 64) {
        const unsigned short* u16 = (const unsigned short*)u;
        float sc = -1e30f;
        if (tid < 63) {
            sc = ab[0];
            for (int t = 0; t < 64; ++t) sc += unph(u16[t * 64 + tid]) * aW[256 + t];
        }
        float m = sc;
#pragma unroll
        for (int off = 32; off; off >>= 1) m = fmaxf(m, __shfl_xor(m, off));
        float e = (tid < 63) ? __expf(sc - m) : 0.f;
        float s = e;
#pragma unroll
        for (int off = 32; off; off >>= 1) s += __shfl_xor(s, off);
        s_attn[tid] = e / s;  // [63] = 0
    }
    __syncthreads();

    // fold time-invariant attention into wih16 (register-local)
#pragma unroll
    for (int j = 0; j < 32; ++j) {
        half2v w = __builtin_bit_cast(half2v, wih16[j]);
        wih16[j] = packh2((float)w.x * s_attn[2 * j], (float)w.y * s_attn[2 * j + 1]);
    }

    // ================= encoder loop =================
    {
        float xa;
        {
            const uint4* xv = (const uint4*)&u[0];
            float a0 = 0.f, a1 = 0.f, a2 = 0.f, a3 = 0.f;
#pragma unroll
            for (int q = 0; q < 8; ++q) {
                uint4 v = xv[q];
                a0 = fdot2f(wih16[4*q+0], v.x, a0);
                a1 = fdot2f(wih16[4*q+1], v.y, a1);
                a2 = fdot2f(wih16[4*q+2], v.z, a2);
                a3 = fdot2f(wih16[4*q+3], v.w, a3);
            }
            xa = (a0 + a1) + (a2 + a3);
        }
        float c = 0.f; // carried by threads 0..127

        for (int t = 0; t < 64; ++t) {
            // gates = act( bias + xa + whh.h )
            float a0 = bias + xa, a1 = 0.f, a2 = 0.f, a3 = 0.f;
#pragma unroll
            for (int q = 0; q < 12; ++q) {
                uint4 hv = *(const uint4*)&s_hch[4 * q];
                a0 = fdot2f(whh16[4*q+0], hv.x, a0);
                a1 = fdot2f(whh16[4*q+1], hv.y, a1);
                a2 = fdot2f(whh16[4*q+2], hv.z, a2);
                a3 = fdot2f(whh16[4*q+3], hv.w, a3);
            }
#pragma unroll
            for (int q = 0; q < 4; ++q) {
                uint4 hv = *(const uint4*)&s_hch[48 + 4 * q];
                a0 = fdot2f(s_wt[(4*q+0)*512 + tid], hv.x, a0);
                a1 = fdot2f(s_wt[(4*q+1)*512 + tid], hv.y, a1);
                a2 = fdot2f(s_wt[(4*q+2)*512 + tid], hv.z, a2);
                a3 = fdot2f(s_wt[(4*q+3)*512 + tid], hv.w, a3);
            }
            const float acc = (a0 + a1) + (a2 + a3);
            const int q = tid >> 7; // 0:i 1:f 2:g 3:o
            s_g[tid] = (q == 2) ? fast_tanh(acc) : fast_sig(acc);
            __syncthreads();
            // state update (2 waves) + next-step x-dot (all waves)
            if (tid < 128) {
                c = s_g[128 + tid] * c + s_g[tid] * s_g[256 + tid];
                float h = s_g[384 + tid] * fast_tanh(c);
                s_enc16[t * 128 + tid] = packh1(h);
                float hx = __shfl_xor(h, 1);
                if (!(tid & 1)) s_hch[tid >> 1] = packh2(h, hx);
            }
            if (t < 63) {
                const uint4* xv = (const uint4*)&u[(t + 1) * 32];
                float b0 = 0.f, b1 = 0.f, b2 = 0.f, b3 = 0.f;
#pragma unroll
                for (int q = 0; q < 8; ++q) {
                    uint4 v = xv[q];
                    b0 = fdot2f(wih16[4*q+0], v.x, b0);
                    b1 = fdot2f(wih16[4*q+1], v.y, b1);
                    b2 = fdot2f(wih16[4*q+2], v.z, b2);
                    b3 = fdot2f(wih16[4*q+3], v.w, b3);
                }
                xa = (b0 + b1) + (b2 + b3);
            }
            __syncthreads();
        }
    }

    // ====== enc_proj epilogue: ep[t][f] = enc[t]@W1e[f] + b1[f] -> u (f16) ======
    {
        const int f = tid & 127, tq = tid >> 7; // 16 t-rows per thread
        float acc[16];
        const float b1 = db1[f];
#pragma unroll
        for (int i = 0; i < 16; ++i) acc[i] = b1;
        const float* w1e = dW1 + f * 384 + 256;
        for (int e0 = 0; e0 < 128; e0 += 8) {
            float4 wa = *(const float4*)&w1e[e0];
            float4 wb = *(const float4*)&w1e[e0 + 4];
            const uint wp0 = packh2(wa.x, wa.y), wp1 = packh2(wa.z, wa.w);
            const uint wp2 = packh2(wb.x, wb.y), wp3 = packh2(wb.z, wb.w);
#pragma unroll
            for (int i = 0; i < 16; ++i) {
                const uint* er = (const uint*)&s_enc16[(tq * 16 + i) * 128 + e0];
                float t0 = fdot2f(wp0, er[0], acc[i]);
                t0 = fdot2f(wp1, er[1], t0);
                t0 = fdot2f(wp2, er[2], t0);
                acc[i] = fdot2f(wp3, er[3], t0);
            }
        }
        // u's encoder contents (x16) have no readers after t=63 -> safe to overwrite
        unsigned short* ep16 = (unsigned short*)u;
#pragma unroll
        for (int i = 0; i < 16; ++i)
            ep16[(tq * 16 + i) * 128 + f] = packh1(acc[i]);
    }

    // ================= decoder prologue =================
    uint w1p[32];
    float bias_d, wih_s;
    const int f4 = tid >> 2, qq = tid & 3;
    const int tp = tid >> 3, p = tid & 7;
    {
#pragma unroll
        for (int j = 0; j < 48; ++j)
            whh16[j] = packh2(dWhh[tid * 128 + 2 * j], dWhh[tid * 128 + 2 * j + 1]);
#pragma unroll
        for (int j = 0; j < 16; ++j)
            s_wt[j * 512 + tid] = packh2(dWhh[tid * 128 + 96 + 2 * j],
                                         dWhh[tid * 128 + 97 + 2 * j]);
        // W1 quarter row f4, pair-chunks rotated by 8*qq (bank spread in P1)
#pragma unroll
        for (int j = 0; j < 32; ++j) {
            const int cj = (j + 8 * qq) & 31;
            w1p[j] = packh2(dW1[f4 * 384 + qq * 64 + 2 * cj],
                            dW1[f4 * 384 + qq * 64 + 2 * cj + 1]);
        }
        bias_d = dbih[tid] + dbhh[tid];
        wih_s  = dWih[tid];
        if (tid < 128) s_hch[tid] = 0u;  // zero [h;c] pairs for decoder
    }
    __syncthreads();

    // ================= decoder loop =================
    {
        float c = 0.f; // carried by threads 0..127

        for (int t = 0; t < 64; ++t) {
            // P1: s_hp[f4] = [h;c] . W1[f4]  (4 lanes per f4, rotated pair reads)
            {
                float a0 = 0.f, a1 = 0.f, a2 = 0.f, a3 = 0.f;
#pragma unroll
                for (int j = 0; j < 32; j += 4) {
                    const int r0 = (j + 8 * qq) & 31;
                    a0 = fdot2f(w1p[j+0], s_hch[qq * 32 + r0], a0);
                    a1 = fdot2f(w1p[j+1], s_hch[qq * 32 + ((j + 1 + 8*qq) & 31)], a1);
                    a2 = fdot2f(w1p[j+2], s_hch[qq * 32 + ((j + 2 + 8*qq) & 31)], a2);
                    a3 = fdot2f(w1p[j+3], s_hch[qq * 32 + ((j + 3 + 8*qq) & 31)], a3);
                }
                float a = (a0 + a1) + (a2 + a3);
                a += __shfl_xor(a, 1);
                a += __shfl_xor(a, 2);
                if (qq == 0) s_hp[f4] = a;
            }
            __syncthreads();
            // P2: score[tp] = sum_f W2[f]*tanh(ep[tp][f]+hp[f])  (8 lanes/tp)
            {
                float a = 0.f;
#pragma unroll
                for (int cc = 0; cc < 4; ++cc) {
                    const int cj = (cc + tp) & 3;
                    const uint* e2 = &u[tp * 64 + p * 8 + cj * 2];
                    const half2v ea = __builtin_bit_cast(half2v, e2[0]);
                    const half2v eb = __builtin_bit_cast(half2v, e2[1]);
                    float4 hv = *(const float4*)&s_hp [p * 16 + cj * 4];
                    float4 wv = *(const float4*)&s_W2v[p * 16 + cj * 4];
                    a += wv.x * fast_tanh((float)ea.x + hv.x);
                    a += wv.y * fast_tanh((float)ea.y + hv.y);
                    a += wv.z * fast_tanh((float)eb.x + hv.z);
                    a += wv.w * fast_tanh((float)eb.y + hv.w);
                }
                a += __shfl_xor(a, 1);
                a += __shfl_xor(a, 2);
                a += __shfl_xor(a, 4);
                if (p == 0) s_sc[tp] = a;
            }
            __syncthreads();
            // P3: softmax over 64 scores (wave 0)
            if (tid < 64) {
                float sc = s_sc[tid];
                float m = sc;
#pragma unroll
                for (int off = 32; off; off >>= 1) m = fmaxf(m, __shfl_xor(m, off));
                float e = __expf(sc - m);
                float s = e;
#pragma unroll
                for (int off = 32; off; off >>= 1) s += __shfl_xor(s, off);
                s_sc[tid] = e / s;
            }
            __syncthreads();
            // P4: context partials over t' quarters (s_enc16 f16)
            {
                const int e = tid & 127, q2 = tid >> 7;
                float a0 = 0.f, a1 = 0.f;
#pragma unroll
                for (int i = 0; i < 16; i += 2) {
                    a0 += s_sc[q2*16 + i]   * unph(s_enc16[(q2*16 + i)   * 128 + e]);
                    a1 += s_sc[q2*16 + i+1] * unph(s_enc16[(q2*16 + i+1) * 128 + e]);
                }
                s_cp[tid] = a0 + a1;
            }
            __syncthreads();
            // P5': wave0 finishes ctx + y_tilde; ALL threads do the whh dot
            if (tid < 64) {
                const float clo = s_cp[tid]       + s_cp[128 + tid]
                                + s_cp[256 + tid] + s_cp[384 + tid];
                const float chi = s_cp[64 + tid]  + s_cp[192 + tid]
                                + s_cp[320 + tid] + s_cp[448 + tid];
                s_ctx[tid]      = clo;
                s_ctx[64 + tid] = chi;
                float a = clo * s_fc[tid] + chi * s_fc[64 + tid];
#pragma unroll
                for (int off = 32; off; off >>= 1) a += __shfl_xor(a, off);
                if (tid == 0) s_yt = a + s_y[t] * s_fc[128] + s_fc[129];
            }
            float a_hh;
            {
                float a0 = bias_d, a1 = 0.f, a2 = 0.f, a3 = 0.f;
#pragma unroll
                for (int q = 0; q < 12; ++q) {
                    uint4 hv = *(const uint4*)&s_hch[4 * q];
                    a0 = fdot2f(whh16[4*q+0], hv.x, a0);
                    a1 = fdot2f(whh16[4*q+1], hv.y, a1);
                    a2 = fdot2f(whh16[4*q+2], hv.z, a2);
                    a3 = fdot2f(whh16[4*q+3], hv.w, a3);
                }
#pragma unroll
                for (int q = 0; q < 4; ++q) {
                    uint4 hv = *(const uint4*)&s_hch[48 + 4 * q];
                    a0 = fdot2f(s_wt[(4*q+0)*512 + tid], hv.x, a0);
                    a1 = fdot2f(s_wt[(4*q+1)*512 + tid], hv.y, a1);
                    a2 = fdot2f(s_wt[(4*q+2)*512 + tid], hv.z, a2);
                    a3 = fdot2f(s_wt[(4*q+3)*512 + tid], hv.w, a3);
                }
                a_hh = (a0 + a1) + (a2 + a3);
            }
            __syncthreads();
            // P6: gates
            {
                const float acc = a_hh + s_yt * wih_s;
                const int q = tid >> 7;
                s_g[tid] = (q == 2) ? fast_tanh(acc) : fast_sig(acc);
            }
            __syncthreads();
            // P7: LSTM state update -> f16 pair state
            if (tid < 128) {
                c = s_g[128 + tid] * c + s_g[tid] * s_g[256 + tid];
                float h = s_g[384 + tid] * fast_tanh(c);
                s_hcf[tid] = h;
                float hx = __shfl_xor(h, 1);
                float cx = __shfl_xor(c, 1);
                if (!(tid & 1)) {
                    s_hch[tid >> 1]        = packh2(h, hx);
                    s_hch[64 + (tid >> 1)] = packh2(c, cx);
                }
            }
            __syncthreads();
        }
    }

    // out[b] = [h, context] . fcf_W + fcf_b
    if (tid < 64) {
        float a = s_hcf[tid]      * fcfW[tid]
                + s_hcf[64 + tid] * fcfW[64 + tid]
                + s_ctx[tid]      * fcfW[128 + tid]
                + s_ctx[64 + tid] * fcfW[192 + tid];
#pragma unroll
        for (int off = 32; off; off >>= 1) a += __shfl_xor(a, off);
        if (tid == 0) out[blockIdx.x] = a + fcfb[0];
    }
}

extern "C" void kernel_launch(void* const* d_in, const int* in_sizes, int n_in,
                              void* d_out, int out_size, void* d_ws, size_t ws_size,
                              hipStream_t stream) {
    const float* x      = (const float*)d_in[0];
    const float* aW     = (const float*)d_in[1];
    const float* ab     = (const float*)d_in[2];
    const float* eWih   = (const float*)d_in[3];
    const float* eWhh   = (const float*)d_in[4];
    const float* ebih   = (const float*)d_in[5];
    const float* ebhh   = (const float*)d_in[6];
    const float* dW1    = (const float*)d_in[7];
    const float* db1    = (const float*)d_in[8];
    const float* W2     = (const float*)d_in[9];
    // d_in[10] = dec_b2: constant added before softmax -> cancels, unused.
    const float* dWih   = (const float*)d_in[11];
    const float* dWhh   = (const float*)d_in[12];
    const float* dbih   = (const float*)d_in[13];
    const float* dbhh   = (const float*)d_in[14];
    const float* fcW    = (const float*)d_in[15];
    const float* fcb    = (const float*)d_in[16];
    const float* fcfW   = (const float*)d_in[17];
    const float* fcfb   = (const float*)d_in[18];
    float* out = (float*)d_out;

    darnn_fused<<<dim3(512), dim3(512), 0, stream>>>(
        x, aW, ab, eWih, eWhh, ebih, ebhh, dW1, db1, W2,
        dWih, dWhh, dbih, dbhh, fcW, fcb, fcfW, fcfb, out);
}